// Round 4
// baseline (925.235 us; speedup 1.0000x reference)
//
#include <hip/hip_runtime.h>
#include <stdint.h>

#define NROWS   131072
#define DDIM    256
#define BM      128
#define BN      160
#define BK      64
#define NWG     8192                  // (131072/128) * (1280/160)
#define NELEM   ((size_t)NROWS * DDIM)

typedef __attribute__((ext_vector_type(8))) short  vbf16x8;   // 8 bf16 in 4 VGPRs
typedef __attribute__((ext_vector_type(4))) float  vf32x4;
typedef __attribute__((ext_vector_type(4))) unsigned int vu32x4;

struct Params {
  const float *x, *lh, *rh, *lc, *rc;
  // weight table [segment][gate]; gates: 0=u 1=i 2=lf 3=rf 4=o
  const float *s0g0, *s0g1, *s0g2, *s0g3, *s0g4;   // seg0: x-side  W_cx W_ix W_fx W_fx W_ox
  const float *s1g0, *s1g1, *s1g2, *s1g3, *s1g4;   // seg1: lh-side U_ulh U_ilh U_lflh U_rflh U_olh
  const float *s2g0, *s2g1, *s2g2, *s2g3, *s2g4;   // seg2: rh-side U_urh U_irh U_lfrh U_rfrh U_orh
  const float *bcx, *bix, *bfx, *box;
  float *out;
};

__device__ __forceinline__ unsigned pk2(float hi, float lo) {
  return __builtin_amdgcn_perm(__float_as_uint(hi), __float_as_uint(lo), 0x07060302u);
}
__device__ __forceinline__ float sigm(float v)  { return 1.f / (1.f + __expf(-v)); }
__device__ __forceinline__ float tanh_(float v) { return 1.f - 2.f / (1.f + __expf(2.f * v)); }
__device__ __forceinline__ const float* sel4(int i, const float* a, const float* b,
                                             const float* c, const float* d) {
  return (i & 2) ? ((i & 1) ? d : c) : ((i & 1) ? b : a);
}

// 512 threads / 8 waves, 128x160 tile. Per-wave output 32x80 -> acc[2][5]=40
// regs. Unified-VGPR lesson (R1-R3): reported VGPR_Count EXCLUDES the 80-reg
// accumulator; R1/R3's 4x5 acc put total ~200 -> 2 waves/SIMD regardless of
// LDS. Here demand ~123 <= 128, so __launch_bounds__(512,4) (cap 128) fits
// WITHOUT the R2 spill disaster -> 4 waves/SIMD.
__global__ __launch_bounds__(512, 4) void fused_tree_cell(Params p)
{
  const int t   = threadIdx.x;
  const int bid = blockIdx.x;
  // XCD-bijective swizzle: col-tile fastest within an XCD chunk.
  const int nbid    = (bid & 7) * (NWG / 8) + (bid >> 3);
  const int tileRow = nbid >> 3;        // 0..1023
  const int cb      = nbid & 7;         // 0..7
  const int rowBase = tileRow * BM;

  __shared__ short As[BM * BK];         // 16 KiB
  __shared__ short Bs[BN * BK];         // 20 KiB

  const int l  = t & 63;
  const int lm = l & 15;
  const int lk = l >> 4;
  const int w  = t >> 6;                // 0..7
  const int wr = w >> 1;                // 0..3 : 32 rows each
  const int wc = w & 1;                 // 0..1 : 80 cols each

  vf32x4 acc[2][5];
#pragma unroll
  for (int m = 0; m < 2; ++m)
#pragma unroll
    for (int n = 0; n < 5; ++n) acc[m][n] = (vf32x4)(0.f);

  float4 aR[2][2];                      // 16 regs in flight
  float4 bR[3][2];                      // 24 regs in flight

  const int tg  = t >> 3;               // 0..63: row within a staging pass
  const int kc  = (t & 7) * 8;          // elem col within BK
  const int kcB = kc * 2;               // byte col within LDS row

  auto stage_load = [&](int kt) {
    const int seg  = kt >> 2;
    const int ksub = (kt & 3) * 64;
    const float *ap, *g0, *g1, *g2, *g3, *g4;
    if (seg == 0)      { ap = p.x;  g0 = p.s0g0; g1 = p.s0g1; g2 = p.s0g2; g3 = p.s0g3; g4 = p.s0g4; }
    else if (seg == 1) { ap = p.lh; g0 = p.s1g0; g1 = p.s1g1; g2 = p.s1g2; g3 = p.s1g3; g4 = p.s1g4; }
    else               { ap = p.rh; g0 = p.s2g0; g1 = p.s2g1; g2 = p.s2g2; g3 = p.s2g3; g4 = p.s2g4; }
    // A: 128 rows in 2 passes of 64
#pragma unroll
    for (int ps = 0; ps < 2; ++ps) {
      const float* s = ap + (size_t)(rowBase + ps * 64 + tg) * DDIM + ksub + kc;
      aR[ps][0] = *(const float4*)s;
      aR[ps][1] = *(const float4*)(s + 4);
    }
    // B: permuted rows n; gate=(n>>4)%5, dloc=(n>=80)*16+(n&15), d=cb*32+dloc.
    { // pass 0: n = tg (0..63) -> gates g0..g3, dloc = tg&15
      const float* bp = sel4(tg >> 4, g0, g1, g2, g3);
      const float* s  = bp + (size_t)(cb * 32 + (tg & 15)) * DDIM + ksub + kc;
      bR[0][0] = *(const float4*)s;
      bR[0][1] = *(const float4*)(s + 4);
    }
    { // pass 1: n = 64+tg -> gates g4,g0,g1,g2; dloc = (tg>=16)*16 + (tg&15)
      const float* bp = sel4(tg >> 4, g4, g0, g1, g2);
      const int dloc  = ((tg >= 16) ? 16 : 0) + (tg & 15);
      const float* s  = bp + (size_t)(cb * 32 + dloc) * DDIM + ksub + kc;
      bR[1][0] = *(const float4*)s;
      bR[1][1] = *(const float4*)(s + 4);
    }
    if (t < 256) { // pass 2: n = 128+tg (tg 0..31) -> g3 then g4; dloc = 16+(tg&15)
      const float* bp = (tg >= 16) ? g4 : g3;
      const float* s  = bp + (size_t)(cb * 32 + 16 + (tg & 15)) * DDIM + ksub + kc;
      bR[2][0] = *(const float4*)s;
      bR[2][1] = *(const float4*)(s + 4);
    }
  };

  auto stage_write = [&]() {
    char* Ab = (char*)&As[0];
#pragma unroll
    for (int ps = 0; ps < 2; ++ps) {
      const int row  = ps * 64 + tg;
      const int byte = (row * 128 + kcB) ^ ((row & 7) << 4);   // T2 XOR swizzle
      vu32x4 v = { pk2(aR[ps][0].y, aR[ps][0].x), pk2(aR[ps][0].w, aR[ps][0].z),
                   pk2(aR[ps][1].y, aR[ps][1].x), pk2(aR[ps][1].w, aR[ps][1].z) };
      *(vu32x4*)(Ab + byte) = v;
    }
    char* Bb = (char*)&Bs[0];
#pragma unroll
    for (int ps = 0; ps < 2; ++ps) {
      const int row  = ps * 64 + tg;
      const int byte = (row * 128 + kcB) ^ ((row & 7) << 4);
      vu32x4 v = { pk2(bR[ps][0].y, bR[ps][0].x), pk2(bR[ps][0].w, bR[ps][0].z),
                   pk2(bR[ps][1].y, bR[ps][1].x), pk2(bR[ps][1].w, bR[ps][1].z) };
      *(vu32x4*)(Bb + byte) = v;
    }
    if (t < 256) {
      const int row  = 128 + tg;
      const int byte = (row * 128 + kcB) ^ ((row & 7) << 4);
      vu32x4 v = { pk2(bR[2][0].y, bR[2][0].x), pk2(bR[2][0].w, bR[2][0].z),
                   pk2(bR[2][1].y, bR[2][1].x), pk2(bR[2][1].w, bR[2][1].z) };
      *(vu32x4*)(Bb + byte) = v;
    }
  };

  auto compute = [&]() {
    const char* Ab = (const char*)&As[0];
    const char* Bb = (const char*)&Bs[0];
    __builtin_amdgcn_s_setprio(1);
#pragma unroll
    for (int ks = 0; ks < 2; ++ks) {
      vbf16x8 af[2], bf[5];
#pragma unroll
      for (int m = 0; m < 2; ++m) {
        const int row  = wr * 32 + m * 16 + lm;
        const int byte = (row * 128 + ks * 64 + lk * 16) ^ ((row & 7) << 4);
        af[m] = *(const vbf16x8*)(Ab + byte);
      }
#pragma unroll
      for (int n = 0; n < 5; ++n) {
        const int row  = wc * 80 + n * 16 + lm;
        const int byte = (row * 128 + ks * 64 + lk * 16) ^ ((row & 7) << 4);
        bf[n] = *(const vbf16x8*)(Bb + byte);
      }
#pragma unroll
      for (int m = 0; m < 2; ++m)
#pragma unroll
        for (int n = 0; n < 5; ++n)
          acc[m][n] = __builtin_amdgcn_mfma_f32_16x16x32_bf16(af[m], bf[n], acc[m][n], 0, 0, 0);
    }
    __builtin_amdgcn_s_setprio(0);
  };

  // prologue
  stage_load(0);
  stage_write();
  __syncthreads();

  // K loop: 768/64 = 12 tiles, single LDS buffer, split barriers (T14).
  for (int kt = 0; kt < 12; ++kt) {
    if (kt < 11) stage_load(kt + 1);    // issue early: latency hides under MFMA
    compute();
    if (kt < 11) {
      __builtin_amdgcn_sched_barrier(0);   // pin ds_reads/MFMA before barrier
      __builtin_amdgcn_s_barrier();        // readers done; NO vmcnt drain here
      stage_write();                        // counted vmcnt at first reg use
      __syncthreads();                      // writes visible for next compute
    }
  }

  // ---- fused epilogue: all 5 gates for this (row, d) live in acc[m][0..4] ----
  const int dcol = cb * 32 + wc * 16 + lm;
  const float bu  = p.bcx[dcol];
  const float bi  = p.bix[dcol];
  const float bff = p.bfx[dcol];
  const float bo  = p.box[dcol];
#pragma unroll
  for (int m = 0; m < 2; ++m) {
    const int r0 = rowBase + wr * 32 + m * 16 + lk * 4;
#pragma unroll
    for (int j = 0; j < 4; ++j) {
      const size_t off = (size_t)(r0 + j) * DDIM + dcol;
      const float pu  = acc[m][0][j] + bu;
      const float pi  = acc[m][1][j] + bi;
      const float plf = acc[m][2][j] + bff;
      const float prf = acc[m][3][j] + bff;
      const float po  = acc[m][4][j] + bo;
      const float u  = tanh_(pu);
      const float ig = sigm(pi);
      const float lf = sigm(plf);
      const float rf = sigm(prf);
      const float og = sigm(po);
      const float c  = ig * u + lf * p.lc[off] + rf * p.rc[off];
      const float h  = og * tanh_(c);
      p.out[off]         = c;
      p.out[NELEM + off] = h;
    }
  }
}

extern "C" void kernel_launch(void* const* d_in, const int* in_sizes, int n_in,
                              void* d_out, int out_size, void* d_ws, size_t ws_size,
                              hipStream_t stream)
{
  Params p;
  p.x  = (const float*)d_in[0];
  p.lc = (const float*)d_in[1];
  p.lh = (const float*)d_in[2];
  p.rc = (const float*)d_in[3];
  p.rh = (const float*)d_in[4];
  const float* W_cx = (const float*)d_in[5];
  const float* b_cx = (const float*)d_in[6];
  const float* W_ox = (const float*)d_in[7];
  const float* b_ox = (const float*)d_in[8];
  const float* W_fx = (const float*)d_in[9];
  const float* b_fx = (const float*)d_in[10];
  const float* W_ix = (const float*)d_in[11];
  const float* b_ix = (const float*)d_in[12];
  const float* U_ilh  = (const float*)d_in[13];
  const float* U_irh  = (const float*)d_in[14];
  const float* U_lflh = (const float*)d_in[15];
  const float* U_lfrh = (const float*)d_in[16];
  const float* U_rflh = (const float*)d_in[17];
  const float* U_rfrh = (const float*)d_in[18];
  const float* U_ulh  = (const float*)d_in[19];
  const float* U_urh  = (const float*)d_in[20];
  const float* U_olh  = (const float*)d_in[21];
  const float* U_orh  = (const float*)d_in[22];

  // gates: 0=u 1=i 2=lf 3=rf 4=o
  p.s0g0 = W_cx;  p.s0g1 = W_ix;  p.s0g2 = W_fx;   p.s0g3 = W_fx;   p.s0g4 = W_ox;
  p.s1g0 = U_ulh; p.s1g1 = U_ilh; p.s1g2 = U_lflh; p.s1g3 = U_rflh; p.s1g4 = U_olh;
  p.s2g0 = U_urh; p.s2g1 = U_irh; p.s2g2 = U_lfrh; p.s2g3 = U_rfrh; p.s2g4 = U_orh;
  p.bcx = b_cx; p.bix = b_ix; p.bfx = b_fx; p.box = b_ox;
  p.out = (float*)d_out;

  hipLaunchKernelGGL(fused_tree_cell, dim3(NWG), dim3(512), 0, stream, p);
}

// Round 5
// 598.085 us; speedup vs baseline: 1.5470x; 1.5470x over previous
//
#include <hip/hip_runtime.h>
#include <stdint.h>

#define NROWS   131072
#define DDIM    256
#define KDIM    768                   // 3 segments x 256
#define BM      128
#define BN      160
#define BK      64
#define NWG     8192                  // (131072/128) * (1280/160)
#define NELEM   ((size_t)NROWS * DDIM)

#define WS_A_BYTES  ((size_t)NROWS * KDIM * 2)          // 201,326,592
#define WS_B_OFF    WS_A_BYTES
#define WS_B_BYTES  ((size_t)8 * 160 * KDIM * 2)        // 1,966,080
#define WS_NEEDED   (WS_A_BYTES + WS_B_BYTES)

typedef __attribute__((ext_vector_type(8))) short  vbf16x8;
typedef __attribute__((ext_vector_type(4))) float  vf32x4;
typedef __attribute__((ext_vector_type(4))) unsigned int vu32x4;

__device__ __forceinline__ unsigned pk2(float hi, float lo) {
  return __builtin_amdgcn_perm(__float_as_uint(hi), __float_as_uint(lo), 0x07060302u);
}
__device__ __forceinline__ float sigm(float v)  { return 1.f / (1.f + __expf(-v)); }
__device__ __forceinline__ float tanh_(float v) { return 1.f - 2.f / (1.f + __expf(2.f * v)); }

// direct-to-LDS 16B load; LDS dest must be wave-uniform (HW adds lane*16)
__device__ __forceinline__ void gload16(const void* g, void* l) {
  __builtin_amdgcn_global_load_lds(
      (const __attribute__((address_space(1))) unsigned int*)g,
      (__attribute__((address_space(3))) unsigned int*)l, 16, 0, 0);
}

// ---------------- prepass A: x|lh|rh fp32 -> A_ws bf16 [131072][768], ----------------
// group-swizzled: within each 128B K-subtile, 16B-group p holds logical group p^(row&7)
__global__ __launch_bounds__(256) void prep_a(const float* __restrict__ x,
                                              const float* __restrict__ lh,
                                              const float* __restrict__ rh,
                                              unsigned short* __restrict__ A_ws)
{
  unsigned gid = blockIdx.x * 256u + threadIdx.x;   // < 131072*96
  unsigned r   = gid / 96u;
  unsigned gc  = gid - r * 96u;                     // logical 8-elem group 0..95
  const float* src = (gc < 32u) ? x : (gc < 64u ? lh : rh);
  const float4* s = (const float4*)(src + (size_t)r * 256u + (gc & 31u) * 8u);
  float4 a0 = s[0], a1 = s[1];
  unsigned p  = (gc & 7u) ^ (r & 7u);               // pre-baked T2 swizzle
  unsigned st = gc >> 3;
  vu32x4 v = { pk2(a0.y, a0.x), pk2(a0.w, a0.z), pk2(a1.y, a1.x), pk2(a1.w, a1.z) };
  *(vu32x4*)(A_ws + (size_t)r * 768u + st * 64u + p * 8u) = v;
}

// ---------------- prepass B: weights -> B_ws bf16 [8 cb][160 n][768] ----------------
// n: gate=(n<80?n:n-80)>>4, dloc=(n>=80)*16+(n&15); d = cb*32+dloc; same group swizzle on n
struct BPrm { const float* w[15]; };                 // [seg 0..2][gate 0..4]
__global__ __launch_bounds__(256) void prep_b(BPrm q, unsigned short* __restrict__ B_ws)
{
  unsigned gid = blockIdx.x * 256u + threadIdx.x;   // < 8*160*96 = 122880
  unsigned cb  = gid / 15360u;
  unsigned rem = gid - cb * 15360u;
  unsigned n   = rem / 96u;
  unsigned gc  = rem - n * 96u;
  unsigned seg  = gc >> 5;
  unsigned gate = (n >= 80u ? n - 80u : n) >> 4;
  unsigned dloc = (n >= 80u ? 16u : 0u) + (n & 15u);
  const float4* s = (const float4*)(q.w[seg * 5 + gate] +
                     (size_t)(cb * 32u + dloc) * 256u + (gc & 31u) * 8u);
  float4 a0 = s[0], a1 = s[1];
  unsigned p = (gc & 7u) ^ (n & 7u);
  vu32x4 v = { pk2(a0.y, a0.x), pk2(a0.w, a0.z), pk2(a1.y, a1.x), pk2(a1.w, a1.z) };
  *(vu32x4*)(B_ws + (size_t)(cb * 160u + n) * 768u + (gc >> 3) * 64u + p * 8u) = v;
}

// ---------------- main fused GEMM + epilogue ----------------
struct GPrm {
  const unsigned short *A, *B;
  const float *lc, *rc, *bcx, *bix, *bfx, *box;
  float* out;
};

__global__ __launch_bounds__(256, 2) void gemm_fused(GPrm p)
{
  const int t   = threadIdx.x;
  const int bid = blockIdx.x;
  const int cb      = bid & 7;        // == XCD (round-robin dispatch): B panel stays in that XCD's L2
  const int rowBase = (bid >> 3) * BM;

  __shared__ unsigned short As[2][BM * BK];   // 2 x 16 KiB
  __shared__ unsigned short Bs[2][BN * BK];   // 2 x 20 KiB

  const int l  = t & 63;
  const int w  = t >> 6;
  const int lm = l & 15;
  const int lk = l >> 4;
  const int wr = w >> 1;               // 0..1: 64 rows
  const int wc = w & 1;                // 0..1: 80 cols

  vf32x4 acc[4][5];
#pragma unroll
  for (int m = 0; m < 4; ++m)
#pragma unroll
    for (int n = 0; n < 5; ++n) acc[m][n] = (vf32x4)(0.f);

  // staging: waves 0,1 -> A (8 calls), waves 2,3 -> B (10 calls). Per call a wave
  // moves 1024B = 8 rows x 128B. Global source is per-lane (swizzle pre-baked),
  // LDS dest wave-uniform + lane*16 (linear).
  const int lr = l >> 3;               // row within 8-row call
  const int lg = l & 7;                // 16B group

  auto issue = [&](int kt, int buf) {
    if (w < 2) {
      const unsigned short* g0 = p.A + (size_t)(rowBase + w * 64 + lr) * 768 + kt * 64 + lg * 8;
      unsigned short* l0 = &As[buf][(w * 64) * 64];
#pragma unroll
      for (int c = 0; c < 8; ++c)
        gload16(g0 + (size_t)c * 8 * 768, l0 + c * 8 * 64);
    } else {
      const unsigned short* g0 = p.B + (size_t)(cb * 160 + (w - 2) * 80 + lr) * 768 + kt * 64 + lg * 8;
      unsigned short* l0 = &Bs[buf][((w - 2) * 80) * 64];
#pragma unroll
      for (int c = 0; c < 10; ++c)
        gload16(g0 + (size_t)c * 8 * 768, l0 + c * 8 * 64);
    }
  };

  auto compute = [&](int buf) {
    const char* Ab = (const char*)&As[buf][0];
    const char* Bb = (const char*)&Bs[buf][0];
    __builtin_amdgcn_s_setprio(1);
#pragma unroll
    for (int ks = 0; ks < 2; ++ks) {
      vbf16x8 af[4], bf[5];
#pragma unroll
      for (int m = 0; m < 4; ++m) {
        const int row  = wr * 64 + m * 16 + lm;
        const int byte = (row * 128 + ks * 64 + lk * 16) ^ ((row & 7) << 4);
        af[m] = *(const vbf16x8*)(Ab + byte);
      }
#pragma unroll
      for (int n = 0; n < 5; ++n) {
        const int row  = wc * 80 + n * 16 + lm;
        const int byte = (row * 128 + ks * 64 + lk * 16) ^ ((row & 7) << 4);
        bf[n] = *(const vbf16x8*)(Bb + byte);
      }
#pragma unroll
      for (int m = 0; m < 4; ++m)
#pragma unroll
        for (int n = 0; n < 5; ++n)
          acc[m][n] = __builtin_amdgcn_mfma_f32_16x16x32_bf16(af[m], bf[n], acc[m][n], 0, 0, 0);
    }
    __builtin_amdgcn_s_setprio(0);
  };

  // T3 minimum-2-phase: STAGE(t+1) issued right AFTER the barrier that drains
  // tile t's loads -> in-flight window = full compute(t) (~1.5k cyc > HBM lat).
  // __syncthreads' vmcnt(0) drain only ever covers the CURRENT tile's loads.
  issue(0, 0);
  for (int kt = 0; kt < 12; ++kt) {
    __syncthreads();
    if (kt < 11) issue(kt + 1, (kt + 1) & 1);
    compute(kt & 1);
  }

  // ---- fused epilogue: 5 gates for (row, d) live in acc[m][0..4] ----
  const int dcol = cb * 32 + wc * 16 + lm;
  const float bu  = p.bcx[dcol];
  const float bi  = p.bix[dcol];
  const float bff = p.bfx[dcol];
  const float bo  = p.box[dcol];
#pragma unroll
  for (int m = 0; m < 4; ++m) {
    const int r0 = rowBase + wr * 64 + m * 16 + lk * 4;
#pragma unroll
    for (int j = 0; j < 4; ++j) {
      const size_t off = (size_t)(r0 + j) * DDIM + dcol;
      const float pu  = acc[m][0][j] + bu;
      const float pi  = acc[m][1][j] + bi;
      const float plf = acc[m][2][j] + bff;
      const float prf = acc[m][3][j] + bff;
      const float po  = acc[m][4][j] + bo;
      const float u  = tanh_(pu);
      const float ig = sigm(pi);
      const float lf = sigm(plf);
      const float rf = sigm(prf);
      const float og = sigm(po);
      const float c  = ig * u + lf * p.lc[off] + rf * p.rc[off];
      const float h  = og * tanh_(c);
      p.out[off]         = c;
      p.out[NELEM + off] = h;
    }
  }
}

// ---------------- fallback (R3 kernel, used only if ws too small) ----------------
struct Params {
  const float *x, *lh, *rh, *lc, *rc;
  const float *s0g0, *s0g1, *s0g2, *s0g3, *s0g4;
  const float *s1g0, *s1g1, *s1g2, *s1g3, *s1g4;
  const float *s2g0, *s2g1, *s2g2, *s2g3, *s2g4;
  const float *bcx, *bix, *bfx, *box;
  float *out;
};
__device__ __forceinline__ const float* sel4(int i, const float* a, const float* b,
                                             const float* c, const float* d) {
  return (i & 2) ? ((i & 1) ? d : c) : ((i & 1) ? b : a);
}
__global__ __launch_bounds__(256, 2) void fused_tree_cell_fb(Params p)
{
  const int t   = threadIdx.x;
  const int bid = blockIdx.x;
  const int nbid    = (bid & 7) * (NWG / 8) + (bid >> 3);
  const int tileRow = nbid >> 3;
  const int cb      = nbid & 7;
  const int rowBase = tileRow * BM;
  __shared__ short As[BM * BK];
  __shared__ short Bs[BN * BK];
  const int l  = t & 63;
  const int lm = l & 15;
  const int lk = l >> 4;
  const int w  = t >> 6;
  const int wr = w >> 1;
  const int wc = w & 1;
  vf32x4 acc[4][5];
#pragma unroll
  for (int m = 0; m < 4; ++m)
#pragma unroll
    for (int n = 0; n < 5; ++n) acc[m][n] = (vf32x4)(0.f);
  float4 aR[4][2];
  float4 bR[5][2];
  const int tg  = t >> 3;
  const int kc  = (t & 7) * 8;
  const int kcB = kc * 2;
  auto stage_load = [&](int kt) {
    const int seg  = kt >> 2;
    const int ksub = (kt & 3) * 64;
    const float *ap, *g0, *g1, *g2, *g3, *g4;
    if (seg == 0)      { ap = p.x;  g0 = p.s0g0; g1 = p.s0g1; g2 = p.s0g2; g3 = p.s0g3; g4 = p.s0g4; }
    else if (seg == 1) { ap = p.lh; g0 = p.s1g0; g1 = p.s1g1; g2 = p.s1g2; g3 = p.s1g3; g4 = p.s1g4; }
    else               { ap = p.rh; g0 = p.s2g0; g1 = p.s2g1; g2 = p.s2g2; g3 = p.s2g3; g4 = p.s2g4; }
#pragma unroll
    for (int ps = 0; ps < 4; ++ps) {
      const float* s = ap + (size_t)(rowBase + ps * 32 + tg) * DDIM + ksub + kc;
      aR[ps][0] = *(const float4*)s;
      aR[ps][1] = *(const float4*)(s + 4);
    }
#define BLOAD(ps, GA, GB) { \
    const float* bp = (t & 128) ? (GB) : (GA); \
    const int dloc = ((((ps) * 32) + tg) >= 80 ? 16 : 0) + (tg & 15); \
    const float* s = bp + (size_t)(cb * 32 + dloc) * DDIM + ksub + kc; \
    bR[ps][0] = *(const float4*)s; \
    bR[ps][1] = *(const float4*)(s + 4); }
    BLOAD(0, g0, g1) BLOAD(1, g2, g3) BLOAD(2, g4, g0) BLOAD(3, g1, g2) BLOAD(4, g3, g4)
#undef BLOAD
  };
  auto stage_write = [&]() {
    char* Ab = (char*)&As[0];
#pragma unroll
    for (int ps = 0; ps < 4; ++ps) {
      const int row  = ps * 32 + tg;
      const int byte = (row * 128 + kcB) ^ ((row & 7) << 4);
      vu32x4 v = { pk2(aR[ps][0].y, aR[ps][0].x), pk2(aR[ps][0].w, aR[ps][0].z),
                   pk2(aR[ps][1].y, aR[ps][1].x), pk2(aR[ps][1].w, aR[ps][1].z) };
      *(vu32x4*)(Ab + byte) = v;
    }
    char* Bb = (char*)&Bs[0];
#pragma unroll
    for (int ps = 0; ps < 5; ++ps) {
      const int row  = ps * 32 + tg;
      const int byte = (row * 128 + kcB) ^ ((row & 7) << 4);
      vu32x4 v = { pk2(bR[ps][0].y, bR[ps][0].x), pk2(bR[ps][0].w, bR[ps][0].z),
                   pk2(bR[ps][1].y, bR[ps][1].x), pk2(bR[ps][1].w, bR[ps][1].z) };
      *(vu32x4*)(Bb + byte) = v;
    }
  };
  auto compute = [&]() {
    const char* Ab = (const char*)&As[0];
    const char* Bb = (const char*)&Bs[0];
    __builtin_amdgcn_s_setprio(1);
#pragma unroll
    for (int ks = 0; ks < 2; ++ks) {
      vbf16x8 af[4], bf[5];
#pragma unroll
      for (int m = 0; m < 4; ++m) {
        const int row  = wr * 64 + m * 16 + lm;
        const int byte = (row * 128 + ks * 64 + lk * 16) ^ ((row & 7) << 4);
        af[m] = *(const vbf16x8*)(Ab + byte);
      }
#pragma unroll
      for (int n = 0; n < 5; ++n) {
        const int row  = wc * 80 + n * 16 + lm;
        const int byte = (row * 128 + ks * 64 + lk * 16) ^ ((row & 7) << 4);
        bf[n] = *(const vbf16x8*)(Bb + byte);
      }
#pragma unroll
      for (int m = 0; m < 4; ++m)
#pragma unroll
        for (int n = 0; n < 5; ++n)
          acc[m][n] = __builtin_amdgcn_mfma_f32_16x16x32_bf16(af[m], bf[n], acc[m][n], 0, 0, 0);
    }
    __builtin_amdgcn_s_setprio(0);
  };
  stage_load(0);
  stage_write();
  __syncthreads();
  for (int kt = 0; kt < 12; ++kt) {
    if (kt < 11) stage_load(kt + 1);
    compute();
    if (kt < 11) {
      __builtin_amdgcn_sched_barrier(0);
      __builtin_amdgcn_s_barrier();
      stage_write();
      __syncthreads();
    }
  }
  const int dcol = cb * 32 + wc * 16 + lm;
  const float bu  = p.bcx[dcol];
  const float bi  = p.bix[dcol];
  const float bff = p.bfx[dcol];
  const float bo  = p.box[dcol];
#pragma unroll
  for (int m = 0; m < 4; ++m) {
    const int r0 = rowBase + wr * 64 + m * 16 + lk * 4;
#pragma unroll
    for (int j = 0; j < 4; ++j) {
      const size_t off = (size_t)(r0 + j) * DDIM + dcol;
      const float pu  = acc[m][0][j] + bu;
      const float pi  = acc[m][1][j] + bi;
      const float plf = acc[m][2][j] + bff;
      const float prf = acc[m][3][j] + bff;
      const float po  = acc[m][4][j] + bo;
      const float u  = tanh_(pu);
      const float ig = sigm(pi);
      const float lf = sigm(plf);
      const float rf = sigm(prf);
      const float og = sigm(po);
      const float c  = ig * u + lf * p.lc[off] + rf * p.rc[off];
      const float h  = og * tanh_(c);
      p.out[off]         = c;
      p.out[NELEM + off] = h;
    }
  }
}

extern "C" void kernel_launch(void* const* d_in, const int* in_sizes, int n_in,
                              void* d_out, int out_size, void* d_ws, size_t ws_size,
                              hipStream_t stream)
{
  const float* x  = (const float*)d_in[0];
  const float* lc = (const float*)d_in[1];
  const float* lh = (const float*)d_in[2];
  const float* rc = (const float*)d_in[3];
  const float* rh = (const float*)d_in[4];
  const float* W_cx = (const float*)d_in[5];
  const float* b_cx = (const float*)d_in[6];
  const float* W_ox = (const float*)d_in[7];
  const float* b_ox = (const float*)d_in[8];
  const float* W_fx = (const float*)d_in[9];
  const float* b_fx = (const float*)d_in[10];
  const float* b_ix = (const float*)d_in[12];
  const float* W_ix = (const float*)d_in[11];
  const float* U_ilh  = (const float*)d_in[13];
  const float* U_irh  = (const float*)d_in[14];
  const float* U_lflh = (const float*)d_in[15];
  const float* U_lfrh = (const float*)d_in[16];
  const float* U_rflh = (const float*)d_in[17];
  const float* U_rfrh = (const float*)d_in[18];
  const float* U_ulh  = (const float*)d_in[19];
  const float* U_urh  = (const float*)d_in[20];
  const float* U_olh  = (const float*)d_in[21];
  const float* U_orh  = (const float*)d_in[22];

  if (ws_size >= WS_NEEDED && d_ws != nullptr) {
    unsigned short* A_ws = (unsigned short*)d_ws;
    unsigned short* B_ws = (unsigned short*)((char*)d_ws + WS_B_OFF);
    hipLaunchKernelGGL(prep_a, dim3(NROWS * 96 / 256), dim3(256), 0, stream, x, lh, rh, A_ws);
    BPrm q;
    q.w[0] = W_cx;  q.w[1] = W_ix;  q.w[2] = W_fx;   q.w[3] = W_fx;   q.w[4] = W_ox;
    q.w[5] = U_ulh; q.w[6] = U_ilh; q.w[7] = U_lflh; q.w[8] = U_rflh; q.w[9] = U_olh;
    q.w[10] = U_urh; q.w[11] = U_irh; q.w[12] = U_lfrh; q.w[13] = U_rfrh; q.w[14] = U_orh;
    hipLaunchKernelGGL(prep_b, dim3(8 * 160 * 96 / 256), dim3(256), 0, stream, q, B_ws);
    GPrm g;
    g.A = A_ws; g.B = B_ws; g.lc = lc; g.rc = rc;
    g.bcx = b_cx; g.bix = b_ix; g.bfx = b_fx; g.box = b_ox;
    g.out = (float*)d_out;
    hipLaunchKernelGGL(gemm_fused, dim3(NWG), dim3(256), 0, stream, g);
  } else {
    Params p;
    p.x = x; p.lc = lc; p.lh = lh; p.rc = rc; p.rh = rh;
    p.s0g0 = W_cx;  p.s0g1 = W_ix;  p.s0g2 = W_fx;   p.s0g3 = W_fx;   p.s0g4 = W_ox;
    p.s1g0 = U_ulh; p.s1g1 = U_ilh; p.s1g2 = U_lflh; p.s1g3 = U_rflh; p.s1g4 = U_olh;
    p.s2g0 = U_urh; p.s2g1 = U_irh; p.s2g2 = U_lfrh; p.s2g3 = U_rfrh; p.s2g4 = U_orh;
    p.bcx = b_cx; p.bix = b_ix; p.bfx = b_fx; p.box = b_ox;
    p.out = (float*)d_out;
    hipLaunchKernelGGL(fused_tree_cell_fb, dim3(NWG), dim3(256), 0, stream, p);
  }
}

// Round 6
// 519.640 us; speedup vs baseline: 1.7805x; 1.1510x over previous
//
#include <hip/hip_runtime.h>
#include <stdint.h>

#define NROWS   131072
#define DDIM    256
#define KDIM    768                   // 3 segments x 256
#define BM      128
#define BN      160
#define BK      64
#define NWG     8192                  // (131072/128) * (1280/160)
#define NELEM   ((size_t)NROWS * DDIM)

#define WS_A_BYTES  ((size_t)NROWS * KDIM * 2)          // 201,326,592
#define WS_B_OFF    WS_A_BYTES
#define WS_B_BYTES  ((size_t)8 * 160 * KDIM * 2)        // 1,966,080
#define WS_NEEDED   (WS_A_BYTES + WS_B_BYTES)

typedef __attribute__((ext_vector_type(8))) short  vbf16x8;
typedef __attribute__((ext_vector_type(4))) float  vf32x4;
typedef __attribute__((ext_vector_type(4))) unsigned int vu32x4;

__device__ __forceinline__ unsigned pk2(float hi, float lo) {
  return __builtin_amdgcn_perm(__float_as_uint(hi), __float_as_uint(lo), 0x07060302u);
}
__device__ __forceinline__ float sigm(float v)  { return 1.f / (1.f + __expf(-v)); }
__device__ __forceinline__ float tanh_(float v) { return 1.f - 2.f / (1.f + __expf(2.f * v)); }

// direct-to-LDS 16B load; LDS dest is wave-uniform base (HW adds lane*16)
__device__ __forceinline__ void gload16(const void* g, void* l) {
  __builtin_amdgcn_global_load_lds(
      (const __attribute__((address_space(1))) unsigned int*)g,
      (__attribute__((address_space(3))) unsigned int*)l, 16, 0, 0);
}

// ---------------- prepass A: x|lh|rh fp32 -> A_ws bf16 [131072][768] ----------------
// group-swizzled: within each 128B K-subtile, 16B-group p holds logical group p^(row&7)
__global__ __launch_bounds__(256) void prep_a(const float* __restrict__ x,
                                              const float* __restrict__ lh,
                                              const float* __restrict__ rh,
                                              unsigned short* __restrict__ A_ws)
{
  unsigned gid = blockIdx.x * 256u + threadIdx.x;   // < 131072*96
  unsigned r   = gid / 96u;
  unsigned gc  = gid - r * 96u;                     // logical 8-elem group 0..95
  const float* src = (gc < 32u) ? x : (gc < 64u ? lh : rh);
  const float4* s = (const float4*)(src + (size_t)r * 256u + (gc & 31u) * 8u);
  float4 a0 = s[0], a1 = s[1];
  unsigned p  = (gc & 7u) ^ (r & 7u);               // pre-baked T2 swizzle
  unsigned st = gc >> 3;
  vu32x4 v = { pk2(a0.y, a0.x), pk2(a0.w, a0.z), pk2(a1.y, a1.x), pk2(a1.w, a1.z) };
  *(vu32x4*)(A_ws + (size_t)r * 768u + st * 64u + p * 8u) = v;
}

// ---------------- prepass B: weights -> B_ws bf16 [8 cb][160 n][768] ----------------
struct BPrm { const float* w[15]; };                 // [seg 0..2][gate 0..4]
__global__ __launch_bounds__(256) void prep_b(BPrm q, unsigned short* __restrict__ B_ws)
{
  unsigned gid = blockIdx.x * 256u + threadIdx.x;   // < 8*160*96 = 122880
  unsigned cb  = gid / 15360u;
  unsigned rem = gid - cb * 15360u;
  unsigned n   = rem / 96u;
  unsigned gc  = rem - n * 96u;
  unsigned seg  = gc >> 5;
  unsigned gate = (n >= 80u ? n - 80u : n) >> 4;
  unsigned dloc = (n >= 80u ? 16u : 0u) + (n & 15u);
  const float4* s = (const float4*)(q.w[seg * 5 + gate] +
                     (size_t)(cb * 32u + dloc) * 256u + (gc & 31u) * 8u);
  float4 a0 = s[0], a1 = s[1];
  unsigned p = (gc & 7u) ^ (n & 7u);
  vu32x4 v = { pk2(a0.y, a0.x), pk2(a0.w, a0.z), pk2(a1.y, a1.x), pk2(a1.w, a1.z) };
  *(vu32x4*)(B_ws + (size_t)(cb * 160u + n) * 768u + (gc >> 3) * 64u + p * 8u) = v;
}

// ---------------- main fused GEMM + epilogue ----------------
struct GPrm {
  const unsigned short *A, *B;
  const float *lc, *rc, *bcx, *bix, *bfx, *box;
  float* out;
};

// 512 threads / 8 waves. Per-wave acc[2][5]=40 regs + frags 28, zero staging
// regs (gload_lds) -> demand ~90 <= 128, so (512,4) is safe (R4's spill came
// from 40 reg-staging VGPRs that no longer exist). 4 waves/SIMD = 16 waves/CU.
__global__ __launch_bounds__(512, 4) void gemm_fused(GPrm p)
{
  const int t   = threadIdx.x;
  const int bid = blockIdx.x;
  const int cb      = bid & 7;        // == XCD (round-robin): same A panel across XCDs concurrently
  const int rowBase = (bid >> 3) * BM;

  __shared__ unsigned short As[2][BM * BK];   // 2 x 16 KiB
  __shared__ unsigned short Bs[2][BN * BK];   // 2 x 20 KiB

  const int l  = t & 63;
  const int w  = t >> 6;               // 0..7
  const int lm = l & 15;
  const int lk = l >> 4;
  const int wr = w >> 1;               // 0..3: 32 rows each
  const int wc = w & 1;                // 0..1: 80 cols each

  vf32x4 acc[2][5];
#pragma unroll
  for (int m = 0; m < 2; ++m)
#pragma unroll
    for (int n = 0; n < 5; ++n) acc[m][n] = (vf32x4)(0.f);

  // staging: waves 0-3 -> A (4 calls, 8 rows/call), waves 4-7 -> B (5 calls).
  const int lr = l >> 3;               // row within 8-row call
  const int lg = l & 7;                // 16B group within 128B row

  auto issue = [&](int kt, int buf) {
    if (w < 4) {
      const unsigned short* g0 = p.A + (size_t)(rowBase + w * 32 + lr) * 768 + kt * 64 + lg * 8;
      unsigned short* l0 = &As[buf][(w * 32) * 64];
#pragma unroll
      for (int c = 0; c < 4; ++c)
        gload16(g0 + (size_t)c * 8 * 768, l0 + c * 8 * 64);
    } else {
      const unsigned short* g0 = p.B + (size_t)(cb * 160 + (w - 4) * 40 + lr) * 768 + kt * 64 + lg * 8;
      unsigned short* l0 = &Bs[buf][((w - 4) * 40) * 64];
#pragma unroll
      for (int c = 0; c < 5; ++c)
        gload16(g0 + (size_t)c * 8 * 768, l0 + c * 8 * 64);
    }
  };

  auto compute = [&](int buf) {
    const char* Ab = (const char*)&As[buf][0];
    const char* Bb = (const char*)&Bs[buf][0];
    __builtin_amdgcn_s_setprio(1);
#pragma unroll
    for (int ks = 0; ks < 2; ++ks) {
      vbf16x8 af[2], bf[5];
#pragma unroll
      for (int m = 0; m < 2; ++m) {
        const int row  = wr * 32 + m * 16 + lm;
        const int byte = (row * 128 + ks * 64 + lk * 16) ^ ((row & 7) << 4);
        af[m] = *(const vbf16x8*)(Ab + byte);
      }
#pragma unroll
      for (int n = 0; n < 5; ++n) {
        const int row  = wc * 80 + n * 16 + lm;
        const int byte = (row * 128 + ks * 64 + lk * 16) ^ ((row & 7) << 4);
        bf[n] = *(const vbf16x8*)(Bb + byte);
      }
#pragma unroll
      for (int m = 0; m < 2; ++m)
#pragma unroll
        for (int n = 0; n < 5; ++n)
          acc[m][n] = __builtin_amdgcn_mfma_f32_16x16x32_bf16(af[m], bf[n], acc[m][n], 0, 0, 0);
    }
    __builtin_amdgcn_s_setprio(0);
  };

  // 2-phase: barrier drains tile-t loads (issued one full compute earlier),
  // then immediately issue t+1 into the other buffer.
  issue(0, 0);
  for (int kt = 0; kt < 12; ++kt) {
    __syncthreads();
    if (kt < 11) issue(kt + 1, (kt + 1) & 1);
    compute(kt & 1);
  }

  // ---- fused epilogue: 5 gates for (row, d) live in acc[m][0..4] ----
  const int dcol = cb * 32 + wc * 16 + lm;
  const float bu  = p.bcx[dcol];
  const float bi  = p.bix[dcol];
  const float bff = p.bfx[dcol];
  const float bo  = p.box[dcol];
#pragma unroll
  for (int m = 0; m < 2; ++m) {
    const int r0 = rowBase + wr * 32 + m * 16 + lk * 4;
#pragma unroll
    for (int j = 0; j < 4; ++j) {
      const size_t off = (size_t)(r0 + j) * DDIM + dcol;
      const float pu  = acc[m][0][j] + bu;
      const float pi  = acc[m][1][j] + bi;
      const float plf = acc[m][2][j] + bff;
      const float prf = acc[m][3][j] + bff;
      const float po  = acc[m][4][j] + bo;
      const float u  = tanh_(pu);
      const float ig = sigm(pi);
      const float lf = sigm(plf);
      const float rf = sigm(prf);
      const float og = sigm(po);
      const float c  = ig * u + lf * p.lc[off] + rf * p.rc[off];
      const float h  = og * tanh_(c);
      p.out[off]         = c;
      p.out[NELEM + off] = h;
    }
  }
}

// ---------------- fallback (R3 kernel, used only if ws too small) ----------------
struct Params {
  const float *x, *lh, *rh, *lc, *rc;
  const float *s0g0, *s0g1, *s0g2, *s0g3, *s0g4;
  const float *s1g0, *s1g1, *s1g2, *s1g3, *s1g4;
  const float *s2g0, *s2g1, *s2g2, *s2g3, *s2g4;
  const float *bcx, *bix, *bfx, *box;
  float *out;
};
__global__ __launch_bounds__(256, 2) void fused_tree_cell_fb(Params p)
{
  const int t   = threadIdx.x;
  const int bid = blockIdx.x;
  const int nbid    = (bid & 7) * (NWG / 8) + (bid >> 3);
  const int tileRow = nbid >> 3;
  const int cb      = nbid & 7;
  const int rowBase = tileRow * BM;
  __shared__ short As[BM * BK];
  __shared__ short Bs[BN * BK];
  const int l  = t & 63;
  const int lm = l & 15;
  const int lk = l >> 4;
  const int w  = t >> 6;
  const int wr = w >> 1;
  const int wc = w & 1;
  vf32x4 acc[4][5];
#pragma unroll
  for (int m = 0; m < 4; ++m)
#pragma unroll
    for (int n = 0; n < 5; ++n) acc[m][n] = (vf32x4)(0.f);
  float4 aR[4][2];
  float4 bR[5][2];
  const int tg  = t >> 3;
  const int kc  = (t & 7) * 8;
  const int kcB = kc * 2;
  auto stage_load = [&](int kt) {
    const int seg  = kt >> 2;
    const int ksub = (kt & 3) * 64;
    const float *ap, *g0, *g1, *g2, *g3, *g4;
    if (seg == 0)      { ap = p.x;  g0 = p.s0g0; g1 = p.s0g1; g2 = p.s0g2; g3 = p.s0g3; g4 = p.s0g4; }
    else if (seg == 1) { ap = p.lh; g0 = p.s1g0; g1 = p.s1g1; g2 = p.s1g2; g3 = p.s1g3; g4 = p.s1g4; }
    else               { ap = p.rh; g0 = p.s2g0; g1 = p.s2g1; g2 = p.s2g2; g3 = p.s2g3; g4 = p.s2g4; }
#pragma unroll
    for (int ps = 0; ps < 4; ++ps) {
      const float* s = ap + (size_t)(rowBase + ps * 32 + tg) * DDIM + ksub + kc;
      aR[ps][0] = *(const float4*)s;
      aR[ps][1] = *(const float4*)(s + 4);
    }
#define BLOAD(ps, GA, GB) { \
    const float* bp = (t & 128) ? (GB) : (GA); \
    const int dloc = ((((ps) * 32) + tg) >= 80 ? 16 : 0) + (tg & 15); \
    const float* s = bp + (size_t)(cb * 32 + dloc) * DDIM + ksub + kc; \
    bR[ps][0] = *(const float4*)s; \
    bR[ps][1] = *(const float4*)(s + 4); }
    BLOAD(0, g0, g1) BLOAD(1, g2, g3) BLOAD(2, g4, g0) BLOAD(3, g1, g2) BLOAD(4, g3, g4)
#undef BLOAD
  };
  auto stage_write = [&]() {
    char* Ab = (char*)&As[0];
#pragma unroll
    for (int ps = 0; ps < 4; ++ps) {
      const int row  = ps * 32 + tg;
      const int byte = (row * 128 + kcB) ^ ((row & 7) << 4);
      vu32x4 v = { pk2(aR[ps][0].y, aR[ps][0].x), pk2(aR[ps][0].w, aR[ps][0].z),
                   pk2(aR[ps][1].y, aR[ps][1].x), pk2(aR[ps][1].w, aR[ps][1].z) };
      *(vu32x4*)(Ab + byte) = v;
    }
    char* Bb = (char*)&Bs[0];
#pragma unroll
    for (int ps = 0; ps < 5; ++ps) {
      const int row  = ps * 32 + tg;
      const int byte = (row * 128 + kcB) ^ ((row & 7) << 4);
      vu32x4 v = { pk2(bR[ps][0].y, bR[ps][0].x), pk2(bR[ps][0].w, bR[ps][0].z),
                   pk2(bR[ps][1].y, bR[ps][1].x), pk2(bR[ps][1].w, bR[ps][1].z) };
      *(vu32x4*)(Bb + byte) = v;
    }
  };
  auto compute = [&]() {
    const char* Ab = (const char*)&As[0];
    const char* Bb = (const char*)&Bs[0];
    __builtin_amdgcn_s_setprio(1);
#pragma unroll
    for (int ks = 0; ks < 2; ++ks) {
      vbf16x8 af[4], bf[5];
#pragma unroll
      for (int m = 0; m < 4; ++m) {
        const int row  = wr * 64 + m * 16 + lm;
        const int byte = (row * 128 + ks * 64 + lk * 16) ^ ((row & 7) << 4);
        af[m] = *(const vbf16x8*)(Ab + byte);
      }
#pragma unroll
      for (int n = 0; n < 5; ++n) {
        const int row  = wc * 80 + n * 16 + lm;
        const int byte = (row * 128 + ks * 64 + lk * 16) ^ ((row & 7) << 4);
        bf[n] = *(const vbf16x8*)(Bb + byte);
      }
#pragma unroll
      for (int m = 0; m < 4; ++m)
#pragma unroll
        for (int n = 0; n < 5; ++n)
          acc[m][n] = __builtin_amdgcn_mfma_f32_16x16x32_bf16(af[m], bf[n], acc[m][n], 0, 0, 0);
    }
    __builtin_amdgcn_s_setprio(0);
  };
  stage_load(0);
  stage_write();
  __syncthreads();
  for (int kt = 0; kt < 12; ++kt) {
    if (kt < 11) stage_load(kt + 1);
    compute();
    if (kt < 11) {
      __builtin_amdgcn_sched_barrier(0);
      __builtin_amdgcn_s_barrier();
      stage_write();
      __syncthreads();
    }
  }
  const int dcol = cb * 32 + wc * 16 + lm;
  const float bu  = p.bcx[dcol];
  const float bi  = p.bix[dcol];
  const float bff = p.bfx[dcol];
  const float bo  = p.box[dcol];
#pragma unroll
  for (int m = 0; m < 4; ++m) {
    const int r0 = rowBase + wr * 64 + m * 16 + lk * 4;
#pragma unroll
    for (int j = 0; j < 4; ++j) {
      const size_t off = (size_t)(r0 + j) * DDIM + dcol;
      const float pu  = acc[m][0][j] + bu;
      const float pi  = acc[m][1][j] + bi;
      const float plf = acc[m][2][j] + bff;
      const float prf = acc[m][3][j] + bff;
      const float po  = acc[m][4][j] + bo;
      const float u  = tanh_(pu);
      const float ig = sigm(pi);
      const float lf = sigm(plf);
      const float rf = sigm(prf);
      const float og = sigm(po);
      const float c  = ig * u + lf * p.lc[off] + rf * p.rc[off];
      const float h  = og * tanh_(c);
      p.out[off]         = c;
      p.out[NELEM + off] = h;
    }
  }
}

extern "C" void kernel_launch(void* const* d_in, const int* in_sizes, int n_in,
                              void* d_out, int out_size, void* d_ws, size_t ws_size,
                              hipStream_t stream)
{
  const float* x  = (const float*)d_in[0];
  const float* lc = (const float*)d_in[1];
  const float* lh = (const float*)d_in[2];
  const float* rc = (const float*)d_in[3];
  const float* rh = (const float*)d_in[4];
  const float* W_cx = (const float*)d_in[5];
  const float* b_cx = (const float*)d_in[6];
  const float* W_ox = (const float*)d_in[7];
  const float* b_ox = (const float*)d_in[8];
  const float* W_fx = (const float*)d_in[9];
  const float* b_fx = (const float*)d_in[10];
  const float* W_ix = (const float*)d_in[11];
  const float* b_ix = (const float*)d_in[12];
  const float* U_ilh  = (const float*)d_in[13];
  const float* U_irh  = (const float*)d_in[14];
  const float* U_lflh = (const float*)d_in[15];
  const float* U_lfrh = (const float*)d_in[16];
  const float* U_rflh = (const float*)d_in[17];
  const float* U_rfrh = (const float*)d_in[18];
  const float* U_ulh  = (const float*)d_in[19];
  const float* U_urh  = (const float*)d_in[20];
  const float* U_olh  = (const float*)d_in[21];
  const float* U_orh  = (const float*)d_in[22];

  if (ws_size >= WS_NEEDED && d_ws != nullptr) {
    unsigned short* A_ws = (unsigned short*)d_ws;
    unsigned short* B_ws = (unsigned short*)((char*)d_ws + WS_B_OFF);
    hipLaunchKernelGGL(prep_a, dim3(NROWS * 96 / 256), dim3(256), 0, stream, x, lh, rh, A_ws);
    BPrm q;
    q.w[0] = W_cx;  q.w[1] = W_ix;  q.w[2] = W_fx;   q.w[3] = W_fx;   q.w[4] = W_ox;
    q.w[5] = U_ulh; q.w[6] = U_ilh; q.w[7] = U_lflh; q.w[8] = U_rflh; q.w[9] = U_olh;
    q.w[10] = U_urh; q.w[11] = U_irh; q.w[12] = U_lfrh; q.w[13] = U_rfrh; q.w[14] = U_orh;
    hipLaunchKernelGGL(prep_b, dim3(8 * 160 * 96 / 256), dim3(256), 0, stream, q, B_ws);
    GPrm g;
    g.A = A_ws; g.B = B_ws; g.lc = lc; g.rc = rc;
    g.bcx = b_cx; g.bix = b_ix; g.bfx = b_fx; g.box = b_ox;
    g.out = (float*)d_out;
    hipLaunchKernelGGL(gemm_fused, dim3(NWG), dim3(512), 0, stream, g);
  } else {
    Params p;
    p.x = x; p.lc = lc; p.lh = lh; p.rc = rc; p.rh = rh;
    p.s0g0 = W_cx;  p.s0g1 = W_ix;  p.s0g2 = W_fx;   p.s0g3 = W_fx;   p.s0g4 = W_ox;
    p.s1g0 = U_ulh; p.s1g1 = U_ilh; p.s1g2 = U_lflh; p.s1g3 = U_rflh; p.s1g4 = U_olh;
    p.s2g0 = U_urh; p.s2g1 = U_irh; p.s2g2 = U_lfrh; p.s2g3 = U_rfrh; p.s2g4 = U_orh;
    p.bcx = b_cx; p.bix = b_ix; p.bfx = b_fx; p.box = b_ox;
    p.out = (float*)d_out;
    hipLaunchKernelGGL(fused_tree_cell_fb, dim3(NWG), dim3(256), 0, stream, p);
  }
}